// Round 2
// 444.439 us; speedup vs baseline: 1.0805x; 1.0805x over previous
//
#include <hip/hip_runtime.h>
#include <math.h>

#define N_NODES 200000
#define BGRAPH  1024
#define HDIM    256
#define ODIM    128
#define SCAP    1024   // max segment length cached in LDS (actual max ~250)

typedef __attribute__((ext_vector_type(8))) short short8;

__device__ __forceinline__ unsigned short f2bf(float f) {
    union { float f; unsigned int i; } c; c.f = f;
    unsigned int i = c.i;
    unsigned int r = i + 0x7FFFu + ((i >> 16) & 1u);  // RNE
    return (unsigned short)(r >> 16);
}
__device__ __forceinline__ float bf2f(unsigned short h) {
    union { unsigned int i; float f; } c; c.i = ((unsigned int)h) << 16;
    return c.f;
}

// ---------------------------------------------------------------------------
// k_prep:
//   blocks 0..255   : v[i] = W[i,:].att_src, u[i] = W[i,:].att_dst
//   blocks 256..260 : segment bounds via binary search (batch sorted)
//   blocks 261..516 : pack GRU weights, bf16 interleaved:
//                     Wg[k][t][0..2] = W_ih[{0,1,2}*256+t][k]
//                     Wg[k][t][3..5] = W_hh[{0,1,2}*256+t][k], [6..7]=0
__global__ __launch_bounds__(256) void k_prep(const float* __restrict__ W,
        const float* __restrict__ att_src, const float* __restrict__ att_dst,
        const int* __restrict__ batch, const float* __restrict__ W_ih,
        const float* __restrict__ W_hh, float* __restrict__ v,
        float* __restrict__ u, int* __restrict__ seg,
        unsigned short* __restrict__ Wg) {
    int t = threadIdx.x;
    if (blockIdx.x < 256) {
        int i = blockIdx.x;
        float w = W[(size_t)i * HDIM + t];
        __shared__ float r1[256], r2[256];
        r1[t] = w * att_src[t];
        r2[t] = w * att_dst[t];
        __syncthreads();
        for (int st = 128; st > 0; st >>= 1) {
            if (t < st) { r1[t] += r1[t + st]; r2[t] += r2[t + st]; }
            __syncthreads();
        }
        if (t == 0) { v[i] = r1[0]; u[i] = r2[0]; }
    } else if (blockIdx.x < 261) {
        int b = (blockIdx.x - 256) * 256 + t;
        if (b > BGRAPH) return;
        if (b == BGRAPH) { seg[b] = N_NODES; return; }
        int lo = 0, hi = N_NODES;
        while (lo < hi) { int mid = (lo + hi) >> 1; if (batch[mid] < b) lo = mid + 1; else hi = mid; }
        seg[b] = lo;
    } else {
        int k = blockIdx.x - 261;            // 0..255
        short8 w8;
        #pragma unroll
        for (int j = 0; j < 3; ++j)
            w8[j] = (short)f2bf(W_ih[(size_t)(j * HDIM + t) * HDIM + k]);
        #pragma unroll
        for (int j = 0; j < 3; ++j)
            w8[3 + j] = (short)f2bf(W_hh[(size_t)(j * HDIM + t) * HDIM + k]);
        w8[6] = 0; w8[7] = 0;
        *(short8*)(Wg + ((size_t)k * HDIM + t) * 8) = w8;
    }
}

// ---------------------------------------------------------------------------
// k_fused: one block per graph b. Entire post-pool recurrence is per-graph
// independent, so: pool + s + smax (HBM sweep), then T=2 iterations of
// {weighted aggregation sweep (L3-hot) -> h = elu(ax@W+b) -> GRU(h, out)},
// then out @ W_lin + b_lin. All state (out, h, s) lives in LDS; zero
// global round-trips between phases, 2 launches total instead of 6.
__global__ __launch_bounds__(256, 4) void k_fused(const float* __restrict__ x,
        const int* __restrict__ seg, const float* __restrict__ v,
        const float* __restrict__ u, const float* __restrict__ W,
        const float* __restrict__ bias_gat, const unsigned short* __restrict__ Wg,
        const float* __restrict__ b_ih, const float* __restrict__ b_hh,
        const float* __restrict__ W_lin, const float* __restrict__ b_lin,
        float* __restrict__ sfall, float* __restrict__ out) {
    int b = blockIdx.x;
    int lo = seg[b], hi = seg[b + 1];
    int t = threadIdx.x, wave = t >> 6, lane = t & 63;

    __shared__ float s_loc[SCAP];        // per-row scores, persists all phases
    __shared__ float comb[4][HDIM];      // cross-wave reduce scratch
    __shared__ float red[256];           // scalar reduce scratch
    __shared__ float axv[HDIM];          // weighted-average vector
    __shared__ float hvec[HDIM];         // GAT output h (GRU input)
    __shared__ float oprev[HDIM];        // running out (pool -> out1 -> out2)
    __shared__ float sred[4], dred[4];

    bool inl = (hi - lo) <= SCAP;
    float ut = u[t];

    // ================= pass 1: pool + s + smax (HBM sweep) =================
    float v0 = v[4 * lane + 0], v1 = v[4 * lane + 1];
    float v2 = v[4 * lane + 2], v3 = v[4 * lane + 3];
    float p0 = 0.f, p1 = 0.f, p2 = 0.f, p3 = 0.f;
    float sm = -3.402823466e38f;
    int i = lo + wave;
    for (; i + 4 < hi; i += 8) {
        const float4 r0 = *(const float4*)(x + (size_t)i * HDIM + 4 * lane);
        const float4 r1 = *(const float4*)(x + (size_t)(i + 4) * HDIM + 4 * lane);
        p0 += r0.x + r1.x; p1 += r0.y + r1.y; p2 += r0.z + r1.z; p3 += r0.w + r1.w;
        float pa = r0.x * v0 + r0.y * v1 + r0.z * v2 + r0.w * v3;
        float pb = r1.x * v0 + r1.y * v1 + r1.z * v2 + r1.w * v3;
        #pragma unroll
        for (int off = 32; off > 0; off >>= 1) {
            pa += __shfl_down(pa, off, 64);
            pb += __shfl_down(pb, off, 64);
        }
        if (lane == 0) {
            if (inl) { s_loc[i - lo] = pa; s_loc[i + 4 - lo] = pb; }
            else     { sfall[i] = pa; sfall[i + 4] = pb; }
            sm = fmaxf(sm, fmaxf(pa, pb));
        }
    }
    for (; i < hi; i += 4) {
        const float4 r0 = *(const float4*)(x + (size_t)i * HDIM + 4 * lane);
        p0 += r0.x; p1 += r0.y; p2 += r0.z; p3 += r0.w;
        float pa = r0.x * v0 + r0.y * v1 + r0.z * v2 + r0.w * v3;
        #pragma unroll
        for (int off = 32; off > 0; off >>= 1) pa += __shfl_down(pa, off, 64);
        if (lane == 0) {
            if (inl) s_loc[i - lo] = pa; else sfall[i] = pa;
            sm = fmaxf(sm, pa);
        }
    }
    comb[wave][4 * lane + 0] = p0; comb[wave][4 * lane + 1] = p1;
    comb[wave][4 * lane + 2] = p2; comb[wave][4 * lane + 3] = p3;
    if (lane == 0) sred[wave] = sm;
    __syncthreads();
    float st0 = comb[0][t] + comb[1][t] + comb[2][t] + comb[3][t];
    oprev[t] = st0;                                  // out0 = pooled sum
    float smx = fmaxf(fmaxf(sred[0], sred[1]), fmaxf(sred[2], sred[3]));
    red[t] = st0 * ut;
    __syncthreads();
    for (int st = 128; st > 0; st >>= 1) { if (t < st) red[t] += red[t + st]; __syncthreads(); }
    float d = red[0];                                // d1 = out0 . u
    __syncthreads();

    // ================= T = 2 recurrence, all block-local =================
    for (int step = 0; step < 2; ++step) {
        float M = smx + d;
        M = M > 0.f ? M : 0.01f * M;                 // max of leakyrelu(s_i+d)

        // ---- weighted aggregation sweep (x is L3-hot after pass 1) ----
        float a0 = 0.f, a1 = 0.f, a2 = 0.f, a3 = 0.f, den = 0.f;
        i = lo + wave;
        for (; i + 12 < hi; i += 16) {
            float s0v = inl ? s_loc[i - lo]      : sfall[i];
            float s1v = inl ? s_loc[i + 4 - lo]  : sfall[i + 4];
            float s2v = inl ? s_loc[i + 8 - lo]  : sfall[i + 8];
            float s3v = inl ? s_loc[i + 12 - lo] : sfall[i + 12];
            float e0 = s0v + d; e0 = e0 > 0.f ? e0 : 0.01f * e0;
            float e1 = s1v + d; e1 = e1 > 0.f ? e1 : 0.01f * e1;
            float e2 = s2v + d; e2 = e2 > 0.f ? e2 : 0.01f * e2;
            float e3 = s3v + d; e3 = e3 > 0.f ? e3 : 0.01f * e3;
            float w0 = __expf(e0 - M), w1 = __expf(e1 - M);
            float w2 = __expf(e2 - M), w3 = __expf(e3 - M);
            const float4 r0 = *(const float4*)(x + (size_t)i * HDIM + 4 * lane);
            const float4 r1 = *(const float4*)(x + (size_t)(i + 4) * HDIM + 4 * lane);
            const float4 r2 = *(const float4*)(x + (size_t)(i + 8) * HDIM + 4 * lane);
            const float4 r3 = *(const float4*)(x + (size_t)(i + 12) * HDIM + 4 * lane);
            den += (w0 + w1) + (w2 + w3);
            a0 += w0 * r0.x + w1 * r1.x + w2 * r2.x + w3 * r3.x;
            a1 += w0 * r0.y + w1 * r1.y + w2 * r2.y + w3 * r3.y;
            a2 += w0 * r0.z + w1 * r1.z + w2 * r2.z + w3 * r3.z;
            a3 += w0 * r0.w + w1 * r1.w + w2 * r2.w + w3 * r3.w;
        }
        for (; i < hi; i += 4) {
            float s0v = inl ? s_loc[i - lo] : sfall[i];
            float e0 = s0v + d; e0 = e0 > 0.f ? e0 : 0.01f * e0;
            float w0 = __expf(e0 - M);
            const float4 r0 = *(const float4*)(x + (size_t)i * HDIM + 4 * lane);
            den += w0;
            a0 += w0 * r0.x; a1 += w0 * r0.y; a2 += w0 * r0.z; a3 += w0 * r0.w;
        }
        comb[wave][4 * lane + 0] = a0; comb[wave][4 * lane + 1] = a1;
        comb[wave][4 * lane + 2] = a2; comb[wave][4 * lane + 3] = a3;
        if (lane == 0) dred[wave] = den;
        __syncthreads();
        float dtot = dred[0] + dred[1] + dred[2] + dred[3];
        float inv = (hi > lo) ? 1.0f / dtot : 0.f;
        axv[t] = (comb[0][t] + comb[1][t] + comb[2][t] + comb[3][t]) * inv;
        __syncthreads();

        // ---- h = elu(ax @ W + bias_gat), W L2-resident, coalesced ----
        float acc = bias_gat[t];
        #pragma unroll 8
        for (int ii = 0; ii < HDIM; ++ii) acc += axv[ii] * W[(size_t)ii * HDIM + t];
        float hval = acc > 0.f ? acc : expm1f(acc);
        __syncthreads();
        hvec[t] = hval;
        __syncthreads();

        // ---- GRU: gi = h@W_ih^T, gh = out@W_hh^T via packed bf16 weights ----
        float gr = 0.f, gz = 0.f, gn = 0.f, hr = 0.f, hz = 0.f, hn = 0.f;
        for (int k0 = 0; k0 < HDIM; k0 += 4) {
            float hq[4], oq[4];
            *(float4*)hq = *(const float4*)&hvec[k0];
            *(float4*)oq = *(const float4*)&oprev[k0];
            #pragma unroll
            for (int j = 0; j < 4; ++j) {
                short8 wv = *(const short8*)(Wg + ((size_t)(k0 + j) * HDIM + t) * 8);
                gr += hq[j] * bf2f((unsigned short)wv[0]);
                gz += hq[j] * bf2f((unsigned short)wv[1]);
                gn += hq[j] * bf2f((unsigned short)wv[2]);
                hr += oq[j] * bf2f((unsigned short)wv[3]);
                hz += oq[j] * bf2f((unsigned short)wv[4]);
                hn += oq[j] * bf2f((unsigned short)wv[5]);
            }
        }
        float gir = gr + b_ih[t];
        float giz = gz + b_ih[HDIM + t];
        float gin = gn + b_ih[2 * HDIM + t];
        float ghr = hr + b_hh[t];
        float ghz = hz + b_hh[HDIM + t];
        float ghn = hn + b_hh[2 * HDIM + t];
        float rg = 1.f / (1.f + __expf(-(gir + ghr)));
        float zg = 1.f / (1.f + __expf(-(giz + ghz)));
        float ng = tanhf(gin + rg * ghn);
        float prev = oprev[t];
        float h2 = (1.f - zg) * ng + zg * prev;
        float no = h2 / (1.f + __expf(-h2));          // silu
        __syncthreads();
        oprev[t] = no;
        red[t] = no * ut;
        __syncthreads();
        for (int st = 128; st > 0; st >>= 1) { if (t < st) red[t] += red[t + st]; __syncthreads(); }
        d = red[0];                                   // d for next timestep
        __syncthreads();
    }

    // ================= final: out2 @ W_lin + b_lin (fp32) =================
    int half = t >> 7, o = t & 127;
    float acc = 0.f;
    #pragma unroll 8
    for (int k = 0; k < 128; ++k)
        acc += oprev[half * 128 + k] * W_lin[(size_t)(half * 128 + k) * ODIM + o];
    red[t] = acc;
    __syncthreads();
    if (t < 128)
        out[(size_t)b * ODIM + t] = red[t] + red[t + 128] + b_lin[t];
}

extern "C" void kernel_launch(void* const* d_in, const int* in_sizes, int n_in,
                              void* d_out, int out_size, void* d_ws, size_t ws_size,
                              hipStream_t stream) {
    const float* x        = (const float*)d_in[0];
    const int*   batch    = (const int*)d_in[1];
    const float* W        = (const float*)d_in[2];
    const float* att_src  = (const float*)d_in[3];
    const float* att_dst  = (const float*)d_in[4];
    const float* bias_gat = (const float*)d_in[5];
    const float* W_ih     = (const float*)d_in[6];
    const float* W_hh     = (const float*)d_in[7];
    const float* b_ih     = (const float*)d_in[8];
    const float* b_hh     = (const float*)d_in[9];
    const float* W_lin    = (const float*)d_in[10];
    const float* b_lin    = (const float*)d_in[11];

    char* ws = (char*)d_ws;
    size_t off = 0;
    auto alloc = [&](size_t bytes) {
        void* p = (void*)(ws + off);
        off += (bytes + 255) & ~(size_t)255;
        return p;
    };
    int*            seg   = (int*)alloc((BGRAPH + 1) * 4);
    float*          vv    = (float*)alloc(HDIM * 4);
    float*          uu    = (float*)alloc(HDIM * 4);
    float*          sfall = (float*)alloc((size_t)N_NODES * 4);
    unsigned short* Wg    = (unsigned short*)alloc((size_t)HDIM * HDIM * 8 * 2);

    hipLaunchKernelGGL(k_prep, dim3(517), dim3(256), 0, stream,
                       W, att_src, att_dst, batch, W_ih, W_hh, vv, uu, seg, Wg);
    hipLaunchKernelGGL(k_fused, dim3(BGRAPH), dim3(256), 0, stream,
                       x, seg, vv, uu, W, bias_gat, Wg, b_ih, b_hh,
                       W_lin, b_lin, sfall, (float*)d_out);
}